// Round 17
// baseline (804.720 us; speedup 1.0000x reference)
//
#include <hip/hip_runtime.h>
#include <hip/hip_bf16.h>

#define NV 778
#define NJ 16
#define NBETA 10
#define NP 135
#define NTHETA 15
#define SD_COLS 2334   // NV*3
#define NBAT 8         // batches per block (single pass)
#define CHUNKP 8       // p's staged per LDS chunk
#define NCHUNK 17      // ceil(135/8)

__device__ __constant__ int c_par[16] = {-1,0,1,2,0,4,5,0,7,8,0,10,11,0,13,14};

struct __align__(4) F3 { float x, y, z; };

// ---------------- Kernel 1: SJ[k][j][c] (10x16x3) and Jt[j][c] (16x3) ----------------
__global__ __launch_bounds__(64) void k_prejoint(
    const float* __restrict__ sd, const float* __restrict__ vt,
    const float* __restrict__ Jr, float* __restrict__ SJ, float* __restrict__ Jt)
{
    const int o = blockIdx.x;
    const int t = threadIdx.x;
    float acc = 0.f;
    if (o < 480) {
        int k = o / 48, rem = o % 48, j = rem / 3, c = rem % 3;
        for (int v = t; v < NV; v += 64) acc += sd[k * SD_COLS + v * 3 + c] * Jr[v * NJ + j];
    } else {
        int idx = o - 480, j = idx / 3, c = idx % 3;
        for (int v = t; v < NV; v += 64) acc += vt[v * 3 + c] * Jr[v * NJ + j];
    }
    #pragma unroll
    for (int off = 32; off > 0; off >>= 1) acc += __shfl_down(acc, off);
    if (t == 0) {
        if (o < 480) SJ[o] = acc;
        else Jt[o - 480] = acc;
    }
}

// ---------------- Kernel 2 (fused): prologue + verts + skinning + joints ------------
// 1024 blocks x 256 thr, single pass of 8 batches. Register pressure held <128 by
// LDS-round-tripping posed verts (vx[24] die before skinning's wrow[16] live).
// pd streamed through LDS in 8-row chunks: 24 independent coalesced loads per chunk
// (one latency exposure), FMAs then read LDS (~60cyc) — fixes r14's per-iteration
// 300cyc VMEM stall (VALUBusy 38%).
__global__ __launch_bounds__(256) void k_fused(
    const float* __restrict__ beta, const float* __restrict__ theta,
    const float* __restrict__ sd, const float* __restrict__ pd,
    const float* __restrict__ vt, const float* __restrict__ Jr,
    const float* __restrict__ W, const float* __restrict__ hm,
    const float* __restrict__ hc, const float* __restrict__ SJ,
    const float* __restrict__ Jt, float* __restrict__ out)
{
    // LDS (36,096 B -> 4 blocks/CU):
    //   region0 [0, 25600): vertLDS[256][25] | pd_chunk[8][768] (24576) | prologue (7680)
    //   [25600, 31744): A_lds[8][16][12]
    //   [31744, 36096): pf_lds[135][8] (+pad)
    __shared__ __align__(16) char smem[25600 + 6144 + 4352];
    float* const vertLDS = (float*)smem;
    float* const pdch    = (float*)smem;               // overlays vertLDS (phase-disjoint)
    float* const A_lds   = (float*)(smem + 25600);
    float* const pf_lds  = (float*)(smem + 25600 + 6144);
    float* const th  = (float*)smem;                   // [8][48]   prologue overlay
    float* const Rsh = (float*)(smem + 1536);          // [8][16][9]
    float* const JLs = (float*)(smem + 1536 + 4608);   // [8][16][3]

    const int tid = threadIdx.x;
    const int bbase = blockIdx.x * NBAT;

    // ---- prologue phase 1: full pose th[b][0..47] ----
    for (int o = tid; o < NBAT * 48; o += 256) {
        int b = o / 48, i = o % 48;
        float acc;
        if (i < 3) {
            acc = theta[(size_t)(bbase + b) * NTHETA + i];
        } else {
            acc = hm[i - 3];
            #pragma unroll
            for (int k = 0; k < 12; ++k)
                acc += theta[(size_t)(bbase + b) * NTHETA + 3 + k] * hc[k * 45 + (i - 3)];
        }
        th[b * 48 + i] = acc;
    }
    __syncthreads();

    // ---- phase 2: Rodrigues + joint positions per (b, j) ----
    if (tid < NBAT * 16) {
        int b = tid >> 4, j = tid & 15;
        float tx = th[b * 48 + 3 * j], ty = th[b * 48 + 3 * j + 1], tz = th[b * 48 + 3 * j + 2];
        float px = tx + 1e-8f, py = ty + 1e-8f, pz = tz + 1e-8f;
        float ang = sqrtf(px * px + py * py + pz * pz);
        float nx = tx / ang, ny = ty / ang, nz = tz / ang;
        float half = 0.5f * ang;
        float w = cosf(half), s = sinf(half);
        float qx = s * nx, qy = s * ny, qz = s * nz;
        float qn = sqrtf(w * w + qx * qx + qy * qy + qz * qz);
        w /= qn; qx /= qn; qy /= qn; qz /= qn;
        float w2 = w * w, x2 = qx * qx, y2 = qy * qy, z2 = qz * qz;
        float wx = w * qx, wy = w * qy, wz = w * qz;
        float xy = qx * qy, xz = qx * qz, yz = qy * qz;
        float* R = Rsh + (b * 16 + j) * 9;
        R[0] = w2 + x2 - y2 - z2; R[1] = 2.f * xy - 2.f * wz; R[2] = 2.f * wy + 2.f * xz;
        R[3] = 2.f * wz + 2.f * xy; R[4] = w2 - x2 + y2 - z2; R[5] = 2.f * yz - 2.f * wx;
        R[6] = 2.f * xz - 2.f * wy; R[7] = 2.f * wx + 2.f * yz; R[8] = w2 - x2 - y2 + z2;
        #pragma unroll
        for (int c = 0; c < 3; ++c) {
            float acc = Jt[j * 3 + c];
            #pragma unroll
            for (int k = 0; k < NBETA; ++k)
                acc += beta[(size_t)(bbase + b) * NBETA + k] * SJ[k * 48 + j * 3 + c];
            JLs[(b * 16 + j) * 3 + c] = acc;
        }
    }
    __syncthreads();

    // ---- phase 3: kinematic chain -> A_lds; pose_feature -> pf_lds ----
    if (tid < NBAT * 16) {
        int b = tid >> 4, j = tid & 15;
        int path[4]; int d = 0; int i = j;
        while (i >= 0) { path[d++] = i; i = c_par[i]; }
        float GR[9], Gt3[3];
        #pragma unroll
        for (int e = 0; e < 9; ++e) GR[e] = Rsh[(b * 16 + 0) * 9 + e];
        Gt3[0] = JLs[(b * 16) * 3 + 0]; Gt3[1] = JLs[(b * 16) * 3 + 1]; Gt3[2] = JLs[(b * 16) * 3 + 2];
        for (int s2 = d - 2; s2 >= 0; --s2) {
            int i2 = path[s2];
            int pa = c_par[i2];
            float ti0 = JLs[(b * 16 + i2) * 3 + 0] - JLs[(b * 16 + pa) * 3 + 0];
            float ti1 = JLs[(b * 16 + i2) * 3 + 1] - JLs[(b * 16 + pa) * 3 + 1];
            float ti2 = JLs[(b * 16 + i2) * 3 + 2] - JLs[(b * 16 + pa) * 3 + 2];
            const float* Ri = Rsh + (b * 16 + i2) * 9;
            float NR[9], Nt[3];
            #pragma unroll
            for (int r = 0; r < 3; ++r) {
                #pragma unroll
                for (int c = 0; c < 3; ++c) {
                    NR[r * 3 + c] = GR[r * 3 + 0] * Ri[0 * 3 + c]
                                  + GR[r * 3 + 1] * Ri[1 * 3 + c]
                                  + GR[r * 3 + 2] * Ri[2 * 3 + c];
                }
                Nt[r] = GR[r * 3 + 0] * ti0 + GR[r * 3 + 1] * ti1 + GR[r * 3 + 2] * ti2 + Gt3[r];
            }
            #pragma unroll
            for (int e = 0; e < 9; ++e) GR[e] = NR[e];
            Gt3[0] = Nt[0]; Gt3[1] = Nt[1]; Gt3[2] = Nt[2];
        }
        float jx = JLs[(b * 16 + j) * 3 + 0], jy = JLs[(b * 16 + j) * 3 + 1], jz = JLs[(b * 16 + j) * 3 + 2];
        float* A = A_lds + (b * 16 + j) * 12;
        #pragma unroll
        for (int r = 0; r < 3; ++r) {
            A[r * 4 + 0] = GR[r * 3 + 0];
            A[r * 4 + 1] = GR[r * 3 + 1];
            A[r * 4 + 2] = GR[r * 3 + 2];
            A[r * 4 + 3] = Gt3[r] - (GR[r * 3 + 0] * jx + GR[r * 3 + 1] * jy + GR[r * 3 + 2] * jz);
        }
        if (j > 0) {
            #pragma unroll
            for (int e = 0; e < 9; ++e) {
                float dlt = (e == 0 || e == 4 || e == 8) ? 1.f : 0.f;
                pf_lds[((j - 1) * 9 + e) * NBAT + b] = Rsh[(b * 16 + j) * 9 + e] - dlt;
            }
        }
    }
    // (chunk loop's leading barrier covers the prologue->region0 handoff)

    // ---- main loop: 4 vertex tiles, 8 batches ----
    const int rb = tid & 7;
    const int rj = (tid >> 3) & 15;
    const int half = tid >> 7;
    float jacc0 = 0.f, jacc1 = 0.f, jacc2 = 0.f;

    #pragma unroll 1
    for (int tile = 0; tile < 4; ++tile) {
        const int vbase = tile * 256;
        const int v = vbase + tid;
        const bool valid = v < NV;
        float vx[NBAT], vy[NBAT], vz[NBAT];

        // shape blend (direct VMEM; 10 iters, F3 loads)
        if (valid) {
            float vt0 = vt[v * 3 + 0], vt1 = vt[v * 3 + 1], vt2 = vt[v * 3 + 2];
            #pragma unroll
            for (int b = 0; b < NBAT; ++b) { vx[b] = vt0; vy[b] = vt1; vz[b] = vt2; }
            #pragma unroll 2
            for (int k = 0; k < NBETA; ++k) {
                F3 s = *(const F3*)(sd + (size_t)k * SD_COLS + v * 3);
                #pragma unroll
                for (int b = 0; b < NBAT; ++b) {
                    float be = beta[(size_t)(bbase + b) * NBETA + k];   // uniform -> s_load
                    vx[b] += be * s.x; vy[b] += be * s.y; vz[b] += be * s.z;
                }
            }
        } else {
            #pragma unroll
            for (int b = 0; b < NBAT; ++b) { vx[b] = 0.f; vy[b] = 0.f; vz[b] = 0.f; }
        }

        // pose blend: pd streamed through LDS in 8-row chunks
        const int cb = vbase * 3;
        #pragma unroll 1
        for (int pc = 0; pc < NCHUNK; ++pc) {
            const int pbase = pc * CHUNKP;
            __syncthreads();   // region0 free (prev chunk consumed / prologue / prev tile)
            #pragma unroll
            for (int pp = 0; pp < CHUNKP; ++pp) {
                int p = pbase + pp; if (p >= NP) p = NP - 1;   // clamp: uniform trip count
                const size_t rowoff = (size_t)p * SD_COLS + cb;
                if (cb + tid < SD_COLS)       pdch[pp * 768 + tid]       = pd[rowoff + tid];
                if (cb + tid + 256 < SD_COLS) pdch[pp * 768 + tid + 256] = pd[rowoff + tid + 256];
                if (cb + tid + 512 < SD_COLS) pdch[pp * 768 + tid + 512] = pd[rowoff + tid + 512];
            }
            __syncthreads();
            if (valid) {
                #pragma unroll
                for (int pp = 0; pp < CHUNKP; ++pp) {
                    const int p = pbase + pp;
                    if (p < NP) {
                        float p0 = pdch[pp * 768 + tid * 3 + 0];
                        float p1 = pdch[pp * 768 + tid * 3 + 1];
                        float p2 = pdch[pp * 768 + tid * 3 + 2];
                        #pragma unroll
                        for (int b = 0; b < NBAT; ++b) {
                            float f = pf_lds[p * NBAT + b];
                            vx[b] += f * p0; vy[b] += f * p1; vz[b] += f * p2;
                        }
                    }
                }
            }
        }
        __syncthreads();   // last chunk reads done before vertLDS overwrite

        // write POSED verts to own vertLDS slots (frees vx/vy/vz registers)
        #pragma unroll
        for (int b = 0; b < NBAT; ++b) {
            vertLDS[tid * 25 + b * 3 + 0] = vx[b];
            vertLDS[tid * 25 + b * 3 + 1] = vy[b];
            vertLDS[tid * 25 + b * 3 + 2] = vz[b];
        }
        // no barrier: each thread reads back only its own slots

        // skinning in-place (posed -> skinned) + finger outputs
        if (valid) {
            float wrow[NJ];
            #pragma unroll
            for (int jc = 0; jc < 4; ++jc) {
                float4 w4 = *(const float4*)(W + (size_t)v * NJ + jc * 4);
                wrow[jc * 4 + 0] = w4.x; wrow[jc * 4 + 1] = w4.y;
                wrow[jc * 4 + 2] = w4.z; wrow[jc * 4 + 3] = w4.w;
            }
            int f = (v == 734) ? 0 : (v == 333) ? 1 : (v == 443) ? 2 : (v == 555) ? 3 : (v == 678) ? 4 : -1;
            #pragma unroll 1
            for (int b = 0; b < NBAT; ++b) {
                float px_ = vertLDS[tid * 25 + b * 3 + 0];
                float py_ = vertLDS[tid * 25 + b * 3 + 1];
                float pz_ = vertLDS[tid * 25 + b * 3 + 2];
                const float* Ab = A_lds + b * 192;
                float ax = 0.f, ay = 0.f, az = 0.f;
                #pragma unroll
                for (int j = 0; j < NJ; ++j) {
                    const float* Aj = Ab + j * 12;
                    float wj = wrow[j];
                    float s0 = Aj[3];  s0 += Aj[0] * px_; s0 += Aj[1]  * py_; s0 += Aj[2]  * pz_;
                    float s1 = Aj[7];  s1 += Aj[4] * px_; s1 += Aj[5]  * py_; s1 += Aj[6]  * pz_;
                    float s2 = Aj[11]; s2 += Aj[8] * px_; s2 += Aj[9]  * py_; s2 += Aj[10] * pz_;
                    ax += wj * s0; ay += wj * s1; az += wj * s2;
                }
                vertLDS[tid * 25 + b * 3 + 0] = ax;
                vertLDS[tid * 25 + b * 3 + 1] = ay;
                vertLDS[tid * 25 + b * 3 + 2] = az;
                if (f >= 0) {
                    size_t o = (size_t)(bbase + b) * 63 + (size_t)(16 + f) * 3;
                    out[o + 0] = ax;
                    out[o + 1] = ay;
                    out[o + 2] = az;
                }
            }
        }
        __syncthreads();   // skinned verts visible to reducers

        // joints[rb][rj] += sum_v Jr[v][rj] * vert[rb][v]  (each half: 128 rows)
        int lim = NV - vbase; if (lim > 256) lim = 256;
        int lo = half * 128;
        int hi = lo + 128; if (hi > lim) hi = lim;
        for (int vv = lo; vv < hi; ++vv) {
            float jr = Jr[(size_t)(vbase + vv) * NJ + rj];
            jacc0 += jr * vertLDS[vv * 25 + rb * 3 + 0];
            jacc1 += jr * vertLDS[vv * 25 + rb * 3 + 1];
            jacc2 += jr * vertLDS[vv * 25 + rb * 3 + 2];
        }
        __syncthreads();
    }

    // combine the two halves' partials via LDS (reuse vertLDS)
    vertLDS[tid * 3 + 0] = jacc0;
    vertLDS[tid * 3 + 1] = jacc1;
    vertLDS[tid * 3 + 2] = jacc2;
    __syncthreads();
    if (tid < 128) {
        float j0 = vertLDS[tid * 3 + 0] + vertLDS[(tid + 128) * 3 + 0];
        float j1 = vertLDS[tid * 3 + 1] + vertLDS[(tid + 128) * 3 + 1];
        float j2 = vertLDS[tid * 3 + 2] + vertLDS[(tid + 128) * 3 + 2];
        size_t o = (size_t)(bbase + rb) * 63 + (size_t)rj * 3;
        out[o + 0] = j0;
        out[o + 1] = j1;
        out[o + 2] = j2;
    }
}

extern "C" void kernel_launch(void* const* d_in, const int* in_sizes, int n_in,
                              void* d_out, int out_size, void* d_ws, size_t ws_size,
                              hipStream_t stream) {
    const float* beta = (const float*)d_in[0];
    const float* theta = (const float*)d_in[1];
    const float* sd   = (const float*)d_in[2];
    const float* pd   = (const float*)d_in[3];
    const float* vt   = (const float*)d_in[4];
    const float* Jr   = (const float*)d_in[5];
    const float* W    = (const float*)d_in[6];
    const float* hm   = (const float*)d_in[7];
    const float* hc   = (const float*)d_in[8];
    float* out = (float*)d_out;

    const int B = in_sizes[0] / NBETA;   // 8192

    float* SJ = (float*)d_ws;            // 480
    float* Jt = SJ + 480;                // 48

    k_prejoint<<<528, 64, 0, stream>>>(sd, vt, Jr, SJ, Jt);
    k_fused<<<B / NBAT, 256, 0, stream>>>(beta, theta, sd, pd, vt, Jr, W, hm, hc, SJ, Jt, out);
}